// Round 3
// baseline (663.114 us; speedup 1.0000x reference)
//
#include <hip/hip_runtime.h>
#include <math.h>

// e0 = 4*((1/3)^12 - (1/3)^6); 0.5*pe = 2*(c12 - c6) - 0.5*e0
static constexpr float HALF_NEG_E0 = 2.739720872e-3f; // -0.5*e0

#define T 256           // threads per block
#define FPSCALE 512.0f  // |f| <= 59.5 -> |int| <= 30464; node sums << 2^31
#define INV_FPSCALE (1.0f / 512.0f)

// ---- Direct-scatter: compute per edge, 2 global int atomics into a 1.2 MB
//      accumulator that lives in L2/L3. (ix,iy) packed into one 64-bit atomic
//      with sign-extended low word: sum decodes exactly (int adds commute ->
//      bit-deterministic). No LDS, no barriers until the energy reduce.
__global__ __launch_bounds__(T)
void lj_direct(const float* __restrict__ bv, const int* __restrict__ dst,
               unsigned long long* __restrict__ accXY, int* __restrict__ accZ,
               float* __restrict__ energy, int E)
{
    const int g  = blockIdx.x * T + threadIdx.x;  // group of 4 edges
    const int e0 = g << 2;
    float esum = 0.0f;

    const float4* __restrict__ bv4 = (const float4*)bv;
    const int4*   __restrict__ d4  = (const int4*)dst;

    auto edge1 = [&](float x, float y, float z, int node) {
        float r2  = x * x + y * y + z * z;
        float inv = 1.0f / r2;
        float c6  = inv * inv * inv;
        float c12 = c6 * c6;
        esum += 2.0f * (c12 - c6) + HALF_NEG_E0;
        float fs = -24.0f * (2.0f * c12 - c6) * inv * FPSCALE;
        int ix = __float2int_rn(fs * x);
        int iy = __float2int_rn(fs * y);
        int iz = __float2int_rn(fs * z);
        // low word sign-extended: high word auto-borrows; decode adds (sx<0).
        unsigned long long p = ((unsigned long long)(unsigned)iy << 32)
                             + (unsigned long long)(long long)ix;
        atomicAdd(&accXY[node], p);
        atomicAdd(&accZ[node], iz);
    };

    if (e0 + 3 < E) {
        // straight-line: all loads issued up front, no barriers in flight path
        float4 a = bv4[3 * g + 0];
        float4 b = bv4[3 * g + 1];
        float4 c = bv4[3 * g + 2];
        int4   d = d4[g];
        edge1(a.x, a.y, a.z, d.x);
        edge1(a.w, b.x, b.y, d.y);
        edge1(b.z, b.w, c.x, d.z);
        edge1(c.y, c.z, c.w, d.w);
    } else if (e0 < E) {
        for (int e = e0; e < E; ++e)
            edge1(bv[3 * e], bv[3 * e + 1], bv[3 * e + 2], dst[e]);
    }

    // ---- energy: wave shuffle -> LDS -> one global atomic per block --------
#pragma unroll
    for (int off = 32; off > 0; off >>= 1)
        esum += __shfl_down(esum, off, 64);
    __shared__ float wsum[T / 64];
    const int wid = threadIdx.x >> 6, lid = threadIdx.x & 63;
    if (lid == 0) wsum[wid] = esum;
    __syncthreads();
    if (threadIdx.x == 0) {
        float s = 0.0f;
        for (int w = 0; w < T / 64; ++w) s += wsum[w];
        unsafeAtomicAdd(energy, s);
    }
}

// ------- Convert: decode packed int sums, write both outputs ----------------
__global__ __launch_bounds__(T)
void lj_convert(const unsigned long long* __restrict__ accXY,
                const int* __restrict__ accZ,
                float* __restrict__ forces, float* __restrict__ analytic, int N)
{
    const int i = blockIdx.x * T + threadIdx.x;   // node index
    if (i >= N) return;
    unsigned long long t = accXY[i];
    int sx = (int)(unsigned)(t & 0xffffffffull);
    int sy = (int)(unsigned)(t >> 32) + (sx < 0 ? 1 : 0);
    int sz = accZ[i];
    float vx = (float)sx * INV_FPSCALE;
    float vy = (float)sy * INV_FPSCALE;
    float vz = (float)sz * INV_FPSCALE;
    analytic[3 * i + 0] = vx;
    analytic[3 * i + 1] = vy;
    analytic[3 * i + 2] = vz;
    forces[3 * i + 0] = -0.5f * vx;
    forces[3 * i + 1] = -0.5f * vy;
    forces[3 * i + 2] = -0.5f * vz;
}

// ---------------- Fallback if workspace too small ---------------------------
__global__ __launch_bounds__(T)
void lj_fallback(const float* __restrict__ bv, const int* __restrict__ dst,
                 float* __restrict__ out_energy, float* __restrict__ analytic, int E)
{
    const int e = blockIdx.x * blockDim.x + threadIdx.x;
    float esum = 0.0f;
    if (e < E) {
        float x = bv[3 * e], y = bv[3 * e + 1], z = bv[3 * e + 2];
        float r2 = x * x + y * y + z * z;
        float inv = 1.0f / r2;
        float c6 = inv * inv * inv, c12 = c6 * c6;
        esum = 2.0f * (c12 - c6) + HALF_NEG_E0;
        float fs = -24.0f * (2.0f * c12 - c6) * inv;
        float* p = analytic + 3 * (size_t)dst[e];
        unsafeAtomicAdd(p + 0, fs * x);
        unsafeAtomicAdd(p + 1, fs * y);
        unsafeAtomicAdd(p + 2, fs * z);
    }
#pragma unroll
    for (int off = 32; off > 0; off >>= 1) esum += __shfl_down(esum, off, 64);
    __shared__ float wsum[T / 64];
    if ((threadIdx.x & 63) == 0) wsum[threadIdx.x >> 6] = esum;
    __syncthreads();
    if (threadIdx.x == 0) {
        float s = 0.0f;
        for (int w = 0; w < T / 64; ++w) s += wsum[w];
        unsafeAtomicAdd(out_energy, s);
    }
}

__global__ __launch_bounds__(T)
void lj_scale(const float* __restrict__ analytic, float* __restrict__ forces, int n)
{
    int i = blockIdx.x * blockDim.x + threadIdx.x;
    if (i < n) forces[i] = -0.5f * analytic[i];
}

extern "C" void kernel_launch(void* const* d_in, const int* in_sizes, int n_in,
                              void* d_out, int out_size, void* d_ws, size_t ws_size,
                              hipStream_t stream)
{
    const float* bv  = (const float*)d_in[0];
    const int*   dst = (const int*)d_in[1];
    const int E = in_sizes[0] / 3;
    const int N = (out_size - 1) / 6;   // out = [energy | forces(3N) | analytic(3N)]
    if (E <= 0 || N <= 0) return;

    float* out      = (float*)d_out;
    float* energy   = out;
    float* forces   = out + 1;
    float* analytic = out + 1 + (size_t)3 * N;

    auto al = [](size_t x) { return (x + 255) & ~(size_t)255; };
    const size_t accXY_bytes = al((size_t)N * 8);
    const size_t accZ_bytes  = al((size_t)N * 4);
    const size_t need = accXY_bytes + accZ_bytes;

    if (ws_size >= need) {
        char* w = (char*)d_ws;
        unsigned long long* accXY = (unsigned long long*)w; w += accXY_bytes;
        int*                accZ  = (int*)w;

        // accXY and accZ are contiguous: one memset covers both (re-poison safe)
        hipMemsetAsync(d_ws, 0, need, stream);
        hipMemsetAsync(energy, 0, sizeof(float), stream);

        const int G = (E + 3) / 4;
        lj_direct <<<(G + T - 1) / T, T, 0, stream>>>(bv, dst, accXY, accZ,
                                                      energy, E);
        lj_convert<<<(N + T - 1) / T, T, 0, stream>>>(accXY, accZ,
                                                      forces, analytic, N);
    } else {
        hipMemsetAsync(d_out, 0, (size_t)out_size * sizeof(float), stream);
        lj_fallback<<<(E + T - 1) / T, T, 0, stream>>>(bv, dst, energy, analytic, E);
        const int n3 = 3 * N;
        lj_scale<<<(n3 + T - 1) / T, T, 0, stream>>>(analytic, forces, n3);
    }
}

// Round 5
// 204.875 us; speedup vs baseline: 3.2367x; 3.2367x over previous
//
#include <hip/hip_runtime.h>
#include <math.h>

// e0 = 4*((1/3)^12 - (1/3)^6); 0.5*pe = 2*(c12 - c6) - 0.5*e0
static constexpr float HALF_NEG_E0 = 2.739720872e-3f; // -0.5*e0

#define T 256           // threads per block
#define B1 2500         // blocks for p3
#define SHIFT 10
#define BK 1024         // nodes per bucket (lid fits in 10 bits)
#define FPSCALE 512.0f  // |f| <= 59.5 -> |int| <= 30450 < 32767
#define INV_FPSCALE (1.0f / 512.0f)

// ---- Phase 3 (fused): count -> reserve (global atomic per bucket) ->
//      compute -> LDS bucket-grouped staging -> coalesced flush --------------
// Requires NB <= 128, GPB*4 >= 128 (launcher guards).  [R0 version, verified 85us]
__global__ __launch_bounds__(T)
void p3_fused(const float* __restrict__ bv, const int* __restrict__ dst,
              unsigned* __restrict__ gcur, int2* __restrict__ sorted,
              float* __restrict__ energy, int E, int NB, int GPB, int cap)
{
    extern __shared__ int smem[];
    const int capb = GPB << 2;                    // max entries per block
    int2*          s_ent = (int2*)smem;           // [capb] packed (lo,hi)
    unsigned char* s_bkt = (unsigned char*)(smem + 2 * capb); // [capb]
    int* lcur = smem + 2 * capb + (capb + 3) / 4; // [NB] counts -> cursors
    int* gml  = lcur + NB;                        // [NB]

    const int r = blockIdx.x;
    const int t = threadIdx.x;

    for (int b = t; b < NB; b += T) lcur[b] = 0;
    __syncthreads();

    const int G  = (E + 3) >> 2;
    const int gs = r * GPB;
    const int ge = min(G, gs + GPB);
    const int4* __restrict__ d4 = (const int4*)dst;

    // ---- pass A: local bucket histogram (native LDS int atomics) -----------
    for (int g = gs + t; g < ge; g += T) {
        const int e0 = g << 2;
        if (e0 + 3 < E) {
            int4 d = d4[g];
            atomicAdd(&lcur[((unsigned)d.x) >> SHIFT], 1);
            atomicAdd(&lcur[((unsigned)d.y) >> SHIFT], 1);
            atomicAdd(&lcur[((unsigned)d.z) >> SHIFT], 1);
            atomicAdd(&lcur[((unsigned)d.w) >> SHIFT], 1);
        } else {
            for (int e = e0; e < E; ++e)
                atomicAdd(&lcur[((unsigned)dst[e]) >> SHIFT], 1);
        }
    }
    __syncthreads();

    // ---- 128-wide exclusive scan of local counts (NB <= 128) ---------------
    int* sc = (int*)s_ent;                        // reuse staging
    if (t < 128) sc[t] = (t < NB) ? lcur[t] : 0;
    __syncthreads();
#pragma unroll
    for (int off = 1; off < 128; off <<= 1) {
        int a0 = (t < 128 && t >= off) ? sc[t - off] : 0;
        __syncthreads();
        if (t < 128) sc[t] += a0;
        __syncthreads();
    }
    // ---- reserve space in each bucket's region (one global atomic each) ----
    if (t < NB) {
        int cnt = lcur[t];
        int ex  = sc[t] - cnt;                    // exclusive prefix
        unsigned ret = atomicAdd(&gcur[t], (unsigned)cnt);
        gml[t]  = t * cap + (int)ret - ex;
        lcur[t] = ex;                             // becomes slot cursor
    }
    __syncthreads();

    // ---- pass B: compute forces + energy, stage bucket-grouped -------------
    const float4* __restrict__ bv4 = (const float4*)bv;
    float esum = 0.0f;

    for (int g = gs + t; g < ge; g += T) {
        const int e0 = g << 2;
        float ex4[4], ey[4], ez[4]; int dd[4];
        int nk;
        if (e0 + 3 < E) {
            float4 a  = bv4[3 * g + 0];
            float4 b2 = bv4[3 * g + 1];
            float4 c  = bv4[3 * g + 2];
            int4 d = d4[g];
            ex4[0] = a.x;  ey[0] = a.y;  ez[0] = a.z;
            ex4[1] = a.w;  ey[1] = b2.x; ez[1] = b2.y;
            ex4[2] = b2.z; ey[2] = b2.w; ez[2] = c.x;
            ex4[3] = c.y;  ey[3] = c.z;  ez[3] = c.w;
            dd[0] = d.x; dd[1] = d.y; dd[2] = d.z; dd[3] = d.w;
            nk = 4;
        } else {
            nk = E - e0;
            for (int k = 0; k < nk; ++k) {
                ex4[k] = bv[3 * (e0 + k) + 0];
                ey[k]  = bv[3 * (e0 + k) + 1];
                ez[k]  = bv[3 * (e0 + k) + 2];
                dd[k]  = dst[e0 + k];
            }
        }
        for (int k = 0; k < nk; ++k) {
            float x = ex4[k], y = ey[k], z = ez[k];
            float r2  = x * x + y * y + z * z;
            float inv = 1.0f / r2;
            float c6  = inv * inv * inv;
            float c12 = c6 * c6;
            esum += 2.0f * (c12 - c6) + HALF_NEG_E0;
            float fs = -24.0f * (2.0f * c12 - c6) * inv * FPSCALE;
            int ix = __float2int_rn(fs * x);
            int iy = __float2int_rn(fs * y);
            int iz = __float2int_rn(fs * z);
            int b  = ((unsigned)dd[k]) >> SHIFT;
            int slot = atomicAdd(&lcur[b], 1);    // native LDS int atomic
            s_ent[slot] = make_int2((ix & 0xffff) | (iy << 16),
                                    (iz & 0xffff) | ((dd[k] & (BK - 1)) << 16));
            s_bkt[slot] = (unsigned char)b;
        }
    }
    __syncthreads();

    // ---- flush: bucket order -> ~208 B contiguous runs ---------------------
    const int nloc = max(0, min(E, ge << 2) - (gs << 2));
    for (int i = t; i < nloc; i += T) {
        int2 e = s_ent[i];
        sorted[gml[(int)s_bkt[i]] + i] = e;
    }

    // ---- energy: wave shuffle -> LDS -> one global atomic per block --------
#pragma unroll
    for (int off = 32; off > 0; off >>= 1)
        esum += __shfl_down(esum, off, 64);
    __shared__ float wsum[T / 64];
    const int wid = t >> 6, lid = t & 63;
    if (lid == 0) wsum[wid] = esum;
    __syncthreads();
    if (t == 0) {
        float s = 0.0f;
        for (int w = 0; w < T / 64; ++w) s += wsum[w];
        unsafeAtomicAdd(energy, s);
    }
}

// ------- Phase 4a: per-(bucket, sub-chunk) partial reduce (int LDS atomics) -
// S2 = 1<<qshift sub-blocks per bucket; qshift in {3,4} (both HW-proven)
__global__ __launch_bounds__(T)
void p4a_partial(const int2* __restrict__ sorted, const unsigned* __restrict__ gcur,
                 int* __restrict__ partial, int cap, int qshift)
{
    __shared__ int acc[BK * 3];                   // 12 KB
    const int S2 = 1 << qshift;
    const int b = blockIdx.x >> qshift;
    const int q = blockIdx.x & (S2 - 1);
    for (int t = threadIdx.x; t < BK * 3; t += T) acc[t] = 0;
    __syncthreads();
    const unsigned len = gcur[b];
    const unsigned s0  = (unsigned)b * (unsigned)cap;   // cap even -> 16B align
    unsigned chunk = (((len + S2 - 1) >> qshift) + 1) & ~1u; // even chunks
    const unsigned c0 = min(len, (unsigned)q * chunk);
    const unsigned c1 = min(len, c0 + chunk);
    for (unsigned i = c0 + 2 * threadIdx.x; i < c1; i += 2 * T) {
        if (i + 1 < c1) {
            int4 v = *(const int4*)(sorted + s0 + i);   // two entries
            int lid0 = ((unsigned)v.y) >> 16;
            atomicAdd(&acc[lid0 * 3 + 0], (int)(short)(v.x & 0xffff));
            atomicAdd(&acc[lid0 * 3 + 1], v.x >> 16);
            atomicAdd(&acc[lid0 * 3 + 2], (int)(short)(v.y & 0xffff));
            int lid1 = ((unsigned)v.w) >> 16;
            atomicAdd(&acc[lid1 * 3 + 0], (int)(short)(v.z & 0xffff));
            atomicAdd(&acc[lid1 * 3 + 1], v.z >> 16);
            atomicAdd(&acc[lid1 * 3 + 2], (int)(short)(v.w & 0xffff));
        } else {
            int2 v = sorted[s0 + i];
            int lid0 = ((unsigned)v.y) >> 16;
            atomicAdd(&acc[lid0 * 3 + 0], (int)(short)(v.x & 0xffff));
            atomicAdd(&acc[lid0 * 3 + 1], v.x >> 16);
            atomicAdd(&acc[lid0 * 3 + 2], (int)(short)(v.y & 0xffff));
        }
    }
    __syncthreads();
    int* P = partial + ((size_t)blockIdx.x) * (BK * 3);
    for (int t = threadIdx.x; t < BK * 3; t += T) P[t] = acc[t];
}

// ------- Phase 4b: merge S2 int partials per bucket, write both outputs -----
__global__ __launch_bounds__(T)
void p4b_merge(const int* __restrict__ partial, float* __restrict__ forces,
               float* __restrict__ analytic, int N, int qshift)
{
    const int i = blockIdx.x * T + threadIdx.x;   // output component idx in [0, 3N)
    if (i >= 3 * N) return;
    const int node = i / 3;
    const int b = node >> SHIFT;
    const int lidc = i - b * (BK * 3);
    const int S2 = 1 << qshift;
    const int* P = partial + ((size_t)(b << qshift)) * (BK * 3) + lidc;
    int s = 0;
    for (int q = 0; q < S2; ++q)
        s += P[(size_t)q * (BK * 3)];
    float v = (float)s * INV_FPSCALE;
    analytic[i] = v;
    forces[i] = -0.5f * v;
}

// ---------------- Fallback (R1 kernel) if workspace too small ---------------
__global__ __launch_bounds__(T)
void lj_fallback(const float* __restrict__ bv, const int* __restrict__ dst,
                 float* __restrict__ out_energy, float* __restrict__ analytic, int E)
{
    const int e = blockIdx.x * blockDim.x + threadIdx.x;
    float esum = 0.0f;
    if (e < E) {
        float x = bv[3 * e], y = bv[3 * e + 1], z = bv[3 * e + 2];
        float r2 = x * x + y * y + z * z;
        float inv = 1.0f / r2;
        float c6 = inv * inv * inv, c12 = c6 * c6;
        esum = 2.0f * (c12 - c6) + HALF_NEG_E0;
        float fs = -24.0f * (2.0f * c12 - c6) * inv;
        float* p = analytic + 3 * (size_t)dst[e];
        unsafeAtomicAdd(p + 0, fs * x);
        unsafeAtomicAdd(p + 1, fs * y);
        unsafeAtomicAdd(p + 2, fs * z);
    }
#pragma unroll
    for (int off = 32; off > 0; off >>= 1) esum += __shfl_down(esum, off, 64);
    __shared__ float wsum[T / 64];
    if ((threadIdx.x & 63) == 0) wsum[threadIdx.x >> 6] = esum;
    __syncthreads();
    if (threadIdx.x == 0) {
        float s = 0.0f;
        for (int w = 0; w < T / 64; ++w) s += wsum[w];
        unsafeAtomicAdd(out_energy, s);
    }
}

__global__ __launch_bounds__(T)
void lj_scale(const float* __restrict__ analytic, float* __restrict__ forces, int n)
{
    int i = blockIdx.x * blockDim.x + threadIdx.x;
    if (i < n) forces[i] = -0.5f * analytic[i];
}

extern "C" void kernel_launch(void* const* d_in, const int* in_sizes, int n_in,
                              void* d_out, int out_size, void* d_ws, size_t ws_size,
                              hipStream_t stream)
{
    const float* bv  = (const float*)d_in[0];
    const int*   dst = (const int*)d_in[1];
    const int E = in_sizes[0] / 3;
    const int N = (out_size - 1) / 6;   // out = [energy | forces(3N) | analytic(3N)]
    if (E <= 0 || N <= 0) return;

    float* out      = (float*)d_out;
    float* energy   = out;
    float* forces   = out + 1;
    float* analytic = out + 1 + (size_t)3 * N;

    const int NB  = (N + BK - 1) / BK;
    const int G   = (E + 3) / 4;
    const int GPB = (G + B1 - 1) / B1;

    // per-bucket region capacity: mean + 10 sigma + 64, rounded even
    const int avg = E / NB;
    int cap = avg + 10 * (int)ceil(sqrt((double)avg)) + 64;
    cap = (cap + 1) & ~1;

    auto al = [](size_t x) { return (x + 255) & ~(size_t)255; };
    const size_t sorted_bytes = al((size_t)NB * cap * 8);
    const size_t gcur_bytes   = al((size_t)NB * 4);

    // adaptive S2: largest power-of-two in {16,8} whose partial fits workspace
    int qshift = -1;
    for (int qs = 4; qs >= 3; --qs) {
        size_t pb = al((size_t)NB * ((size_t)1 << qs) * (BK * 3) * 4);
        if (sorted_bytes + gcur_bytes + pb <= ws_size) { qshift = qs; break; }
    }

    const int capb = GPB * 4;
    // staging int2[capb] + uchar[capb] (rounded to ints) + 2*NB ints
    const size_t smem_bytes = (size_t)capb * 8 + ((size_t)(capb + 3) / 4) * 4
                            + (size_t)2 * NB * 4;

    if (NB <= 128 && capb >= 128 && smem_bytes <= 64000 && qshift >= 3) {
        char* w = (char*)d_ws;
        int2*     sorted  = (int2*)w;      w += sorted_bytes;
        unsigned* gcur    = (unsigned*)w;  w += gcur_bytes;
        int*      partial = (int*)w;

        hipMemsetAsync(gcur, 0, (size_t)NB * 4, stream);
        hipMemsetAsync(energy, 0, sizeof(float), stream);
        p3_fused   <<<B1, T, smem_bytes, stream>>>(bv, dst, gcur, sorted, energy,
                                                   E, NB, GPB, cap);
        p4a_partial<<<NB << qshift, T, 0, stream>>>(sorted, gcur, partial, cap, qshift);
        p4b_merge  <<<(3 * N + T - 1) / T, T, 0, stream>>>(partial, forces, analytic,
                                                           N, qshift);
    } else {
        hipMemsetAsync(d_out, 0, (size_t)out_size * sizeof(float), stream);
        lj_fallback<<<(E + T - 1) / T, T, 0, stream>>>(bv, dst, energy, analytic, E);
        const int n3 = 3 * N;
        lj_scale<<<(n3 + T - 1) / T, T, 0, stream>>>(analytic, forces, n3);
    }
}

// Round 7
// 202.155 us; speedup vs baseline: 3.2802x; 1.0135x over previous
//
#include <hip/hip_runtime.h>
#include <math.h>

// e0 = 4*((1/3)^12 - (1/3)^6); 0.5*pe = 2*(c12 - c6) - 0.5*e0
static constexpr float HALF_NEG_E0 = 2.739720872e-3f; // -0.5*e0

#define T 256           // threads per block
#define B1 2500         // blocks for p3
#define SHIFT 10
#define BK 1024         // nodes per bucket (lid fits in 10 bits)
#define QS 3            // log2 sub-blocks per bucket in p4a (S2=8, R0-proven)
#define FPSCALE 512.0f  // |f| <= 59.5 -> |int| <= 30450 < 32767
#define INV_FPSCALE (1.0f / 512.0f)

// ---- Phase 3 (fused): count -> reserve (global atomic per bucket) ->
//      compute -> LDS bucket-grouped staging -> coalesced flush --------------
// Requires NB <= 128, GPB*4 >= 128 (launcher guards).  [R0 version, verified 83us]
__global__ __launch_bounds__(T)
void p3_fused(const float* __restrict__ bv, const int* __restrict__ dst,
              unsigned* __restrict__ gcur, int2* __restrict__ sorted,
              float* __restrict__ energy, int E, int NB, int GPB, int cap)
{
    extern __shared__ int smem[];
    const int capb = GPB << 2;                    // max entries per block
    int2*          s_ent = (int2*)smem;           // [capb] packed (lo,hi)
    unsigned char* s_bkt = (unsigned char*)(smem + 2 * capb); // [capb]
    int* lcur = smem + 2 * capb + (capb + 3) / 4; // [NB] counts -> cursors
    int* gml  = lcur + NB;                        // [NB]

    const int r = blockIdx.x;
    const int t = threadIdx.x;

    for (int b = t; b < NB; b += T) lcur[b] = 0;
    __syncthreads();

    const int G  = (E + 3) >> 2;
    const int gs = r * GPB;
    const int ge = min(G, gs + GPB);
    const int4* __restrict__ d4 = (const int4*)dst;

    // ---- pass A: local bucket histogram (native LDS int atomics) -----------
    for (int g = gs + t; g < ge; g += T) {
        const int e0 = g << 2;
        if (e0 + 3 < E) {
            int4 d = d4[g];
            atomicAdd(&lcur[((unsigned)d.x) >> SHIFT], 1);
            atomicAdd(&lcur[((unsigned)d.y) >> SHIFT], 1);
            atomicAdd(&lcur[((unsigned)d.z) >> SHIFT], 1);
            atomicAdd(&lcur[((unsigned)d.w) >> SHIFT], 1);
        } else {
            for (int e = e0; e < E; ++e)
                atomicAdd(&lcur[((unsigned)dst[e]) >> SHIFT], 1);
        }
    }
    __syncthreads();

    // ---- 128-wide exclusive scan of local counts (NB <= 128) ---------------
    int* sc = (int*)s_ent;                        // reuse staging
    if (t < 128) sc[t] = (t < NB) ? lcur[t] : 0;
    __syncthreads();
#pragma unroll
    for (int off = 1; off < 128; off <<= 1) {
        int a0 = (t < 128 && t >= off) ? sc[t - off] : 0;
        __syncthreads();
        if (t < 128) sc[t] += a0;
        __syncthreads();
    }
    // ---- reserve space in each bucket's region (one global atomic each) ----
    if (t < NB) {
        int cnt = lcur[t];
        int ex  = sc[t] - cnt;                    // exclusive prefix
        unsigned ret = atomicAdd(&gcur[t], (unsigned)cnt);
        gml[t]  = t * cap + (int)ret - ex;
        lcur[t] = ex;                             // becomes slot cursor
    }
    __syncthreads();

    // ---- pass B: compute forces + energy, stage bucket-grouped -------------
    const float4* __restrict__ bv4 = (const float4*)bv;
    float esum = 0.0f;

    for (int g = gs + t; g < ge; g += T) {
        const int e0 = g << 2;
        float ex4[4], ey[4], ez[4]; int dd[4];
        int nk;
        if (e0 + 3 < E) {
            float4 a  = bv4[3 * g + 0];
            float4 b2 = bv4[3 * g + 1];
            float4 c  = bv4[3 * g + 2];
            int4 d = d4[g];
            ex4[0] = a.x;  ey[0] = a.y;  ez[0] = a.z;
            ex4[1] = a.w;  ey[1] = b2.x; ez[1] = b2.y;
            ex4[2] = b2.z; ey[2] = b2.w; ez[2] = c.x;
            ex4[3] = c.y;  ey[3] = c.z;  ez[3] = c.w;
            dd[0] = d.x; dd[1] = d.y; dd[2] = d.z; dd[3] = d.w;
            nk = 4;
        } else {
            nk = E - e0;
            for (int k = 0; k < nk; ++k) {
                ex4[k] = bv[3 * (e0 + k) + 0];
                ey[k]  = bv[3 * (e0 + k) + 1];
                ez[k]  = bv[3 * (e0 + k) + 2];
                dd[k]  = dst[e0 + k];
            }
        }
        for (int k = 0; k < nk; ++k) {
            float x = ex4[k], y = ey[k], z = ez[k];
            float r2  = x * x + y * y + z * z;
            float inv = 1.0f / r2;
            float c6  = inv * inv * inv;
            float c12 = c6 * c6;
            esum += 2.0f * (c12 - c6) + HALF_NEG_E0;
            float fs = -24.0f * (2.0f * c12 - c6) * inv * FPSCALE;
            int ix = __float2int_rn(fs * x);
            int iy = __float2int_rn(fs * y);
            int iz = __float2int_rn(fs * z);
            int b  = ((unsigned)dd[k]) >> SHIFT;
            int slot = atomicAdd(&lcur[b], 1);    // native LDS int atomic
            s_ent[slot] = make_int2((ix & 0xffff) | (iy << 16),
                                    (iz & 0xffff) | ((dd[k] & (BK - 1)) << 16));
            s_bkt[slot] = (unsigned char)b;
        }
    }
    __syncthreads();

    // ---- flush: bucket order -> ~208 B contiguous runs ---------------------
    const int nloc = max(0, min(E, ge << 2) - (gs << 2));
    for (int i = t; i < nloc; i += T) {
        int2 e = s_ent[i];
        sorted[gml[(int)s_bkt[i]] + i] = e;
    }

    // ---- energy: wave shuffle -> LDS -> one global atomic per block --------
#pragma unroll
    for (int off = 32; off > 0; off >>= 1)
        esum += __shfl_down(esum, off, 64);
    __shared__ float wsum[T / 64];
    const int wid = t >> 6, lid = t & 63;
    if (lid == 0) wsum[wid] = esum;
    __syncthreads();
    if (t == 0) {
        float s = 0.0f;
        for (int w = 0; w < T / 64; ++w) s += wsum[w];
        unsafeAtomicAdd(energy, s);
    }
}

// ------- Phase 4a: per-(bucket, sub-chunk) partial reduce -------------------
// Packed 64-bit LDS atomics: (ix,iy) in one ds_add_u64 (sign-extension carry
// trick, exact for int sums); 2 atomics/entry instead of 3. Main loop issues
// 4 coalesced int4 loads (MLP=4) before consuming.
__global__ __launch_bounds__(T)
void p4a_partial(const int2* __restrict__ sorted, const unsigned* __restrict__ gcur,
                 unsigned long long* __restrict__ partXY, int* __restrict__ partZ,
                 int cap)
{
    __shared__ unsigned long long accXY[BK];      // 8 KB
    __shared__ int accZ[BK];                      // 4 KB
    const int S2 = 1 << QS;
    const int b = blockIdx.x >> QS;
    const int q = blockIdx.x & (S2 - 1);
    for (int t = threadIdx.x; t < BK; t += T) { accXY[t] = 0ull; accZ[t] = 0; }
    __syncthreads();
    const unsigned len = gcur[b];
    const unsigned s0  = (unsigned)b * (unsigned)cap;   // cap even -> 16B align
    unsigned chunk = (((len + S2 - 1) >> QS) + 1) & ~1u; // even chunks
    const unsigned c0 = min(len, (unsigned)q * chunk);
    const unsigned c1 = min(len, c0 + chunk);

    auto acc2 = [&](int4 v) {                     // two entries
        int lid0 = ((unsigned)v.y) >> 16;
        int ix0  = (int)(short)(v.x & 0xffff);
        int iy0  = v.x >> 16;
        unsigned long long p0 = ((unsigned long long)(unsigned)iy0 << 32)
                              + (unsigned long long)(long long)ix0;
        atomicAdd(&accXY[lid0], p0);
        atomicAdd(&accZ[lid0], (int)(short)(v.y & 0xffff));
        int lid1 = ((unsigned)v.w) >> 16;
        int ix1  = (int)(short)(v.z & 0xffff);
        int iy1  = v.z >> 16;
        unsigned long long p1 = ((unsigned long long)(unsigned)iy1 << 32)
                              + (unsigned long long)(long long)ix1;
        atomicAdd(&accXY[lid1], p1);
        atomicAdd(&accZ[lid1], (int)(short)(v.w & 0xffff));
    };
    auto acc1 = [&](int2 v) {
        int lid0 = ((unsigned)v.y) >> 16;
        int ix0  = (int)(short)(v.x & 0xffff);
        int iy0  = v.x >> 16;
        unsigned long long p0 = ((unsigned long long)(unsigned)iy0 << 32)
                              + (unsigned long long)(long long)ix0;
        atomicAdd(&accXY[lid0], p0);
        atomicAdd(&accZ[lid0], (int)(short)(v.y & 0xffff));
    };

    unsigned base = c0 + 2 * threadIdx.x;
    // 4-deep MLP main loop: 4 coalesced int4 loads at strides 0,2T,4T,6T
    for (; base + 6 * T + 1 < c1; base += 8 * T) {
        int4 v0 = *(const int4*)(sorted + s0 + base);
        int4 v1 = *(const int4*)(sorted + s0 + base + 2 * T);
        int4 v2 = *(const int4*)(sorted + s0 + base + 4 * T);
        int4 v3 = *(const int4*)(sorted + s0 + base + 6 * T);
        acc2(v0); acc2(v1); acc2(v2); acc2(v3);
    }
    for (; base < c1; base += 2 * T) {
        if (base + 1 < c1) acc2(*(const int4*)(sorted + s0 + base));
        else               acc1(sorted[s0 + base]);
    }
    __syncthreads();
    unsigned long long* PX = partXY + (size_t)blockIdx.x * BK;
    int*                PZ = partZ  + (size_t)blockIdx.x * BK;
    for (int t = threadIdx.x; t < BK; t += T) { PX[t] = accXY[t]; PZ[t] = accZ[t]; }
}

// ------- Phase 4b: merge S2 packed partials per node, write both outputs ----
__global__ __launch_bounds__(T)
void p4b_merge(const unsigned long long* __restrict__ partXY,
               const int* __restrict__ partZ,
               float* __restrict__ forces, float* __restrict__ analytic, int N)
{
    const int node = blockIdx.x * T + threadIdx.x;
    if (node >= N) return;
    const int b   = node >> SHIFT;
    const int lid = node & (BK - 1);
    const int S2  = 1 << QS;
    const unsigned long long* PX = partXY + ((size_t)(b << QS)) * BK + lid;
    const int*                PZ = partZ  + ((size_t)(b << QS)) * BK + lid;
    unsigned long long sxy = 0ull; int sz = 0;
#pragma unroll
    for (int q = 0; q < S2; ++q) {
        sxy += PX[(size_t)q * BK];
        sz  += PZ[(size_t)q * BK];
    }
    int sx = (int)(unsigned)(sxy & 0xffffffffull);
    int sy = (int)(unsigned)(sxy >> 32) + (sx < 0 ? 1 : 0);
    float vx = (float)sx * INV_FPSCALE;
    float vy = (float)sy * INV_FPSCALE;
    float vz = (float)sz * INV_FPSCALE;
    analytic[3 * node + 0] = vx;
    analytic[3 * node + 1] = vy;
    analytic[3 * node + 2] = vz;
    forces[3 * node + 0] = -0.5f * vx;
    forces[3 * node + 1] = -0.5f * vy;
    forces[3 * node + 2] = -0.5f * vz;
}

// ---------------- Fallback (R1 kernel) if workspace too small ---------------
__global__ __launch_bounds__(T)
void lj_fallback(const float* __restrict__ bv, const int* __restrict__ dst,
                 float* __restrict__ out_energy, float* __restrict__ analytic, int E)
{
    const int e = blockIdx.x * blockDim.x + threadIdx.x;
    float esum = 0.0f;
    if (e < E) {
        float x = bv[3 * e], y = bv[3 * e + 1], z = bv[3 * e + 2];
        float r2 = x * x + y * y + z * z;
        float inv = 1.0f / r2;
        float c6 = inv * inv * inv, c12 = c6 * c6;
        esum = 2.0f * (c12 - c6) + HALF_NEG_E0;
        float fs = -24.0f * (2.0f * c12 - c6) * inv;
        float* p = analytic + 3 * (size_t)dst[e];
        unsafeAtomicAdd(p + 0, fs * x);
        unsafeAtomicAdd(p + 1, fs * y);
        unsafeAtomicAdd(p + 2, fs * z);
    }
#pragma unroll
    for (int off = 32; off > 0; off >>= 1) esum += __shfl_down(esum, off, 64);
    __shared__ float wsum[T / 64];
    if ((threadIdx.x & 63) == 0) wsum[threadIdx.x >> 6] = esum;
    __syncthreads();
    if (threadIdx.x == 0) {
        float s = 0.0f;
        for (int w = 0; w < T / 64; ++w) s += wsum[w];
        unsafeAtomicAdd(out_energy, s);
    }
}

__global__ __launch_bounds__(T)
void lj_scale(const float* __restrict__ analytic, float* __restrict__ forces, int n)
{
    int i = blockIdx.x * blockDim.x + threadIdx.x;
    if (i < n) forces[i] = -0.5f * analytic[i];
}

extern "C" void kernel_launch(void* const* d_in, const int* in_sizes, int n_in,
                              void* d_out, int out_size, void* d_ws, size_t ws_size,
                              hipStream_t stream)
{
    const float* bv  = (const float*)d_in[0];
    const int*   dst = (const int*)d_in[1];
    const int E = in_sizes[0] / 3;
    const int N = (out_size - 1) / 6;   // out = [energy | forces(3N) | analytic(3N)]
    if (E <= 0 || N <= 0) return;

    float* out      = (float*)d_out;
    float* energy   = out;
    float* forces   = out + 1;
    float* analytic = out + 1 + (size_t)3 * N;

    const int NB  = (N + BK - 1) / BK;
    const int G   = (E + 3) / 4;
    const int GPB = (G + B1 - 1) / B1;

    // per-bucket region capacity: mean + 10 sigma + 64, rounded even
    const int avg = E / NB;
    int cap = avg + 10 * (int)ceil(sqrt((double)avg)) + 64;
    cap = (cap + 1) & ~1;

    auto al = [](size_t x) { return (x + 255) & ~(size_t)255; };
    const size_t sorted_bytes = al((size_t)NB * cap * 8);
    const size_t gcur_bytes   = al((size_t)NB * 4);
    const size_t partXY_bytes = al((size_t)NB * (1 << QS) * BK * 8);
    const size_t partZ_bytes  = al((size_t)NB * (1 << QS) * BK * 4);
    const size_t need = sorted_bytes + gcur_bytes + partXY_bytes + partZ_bytes;

    const int capb = GPB * 4;
    // staging int2[capb] + uchar[capb] (rounded to ints) + 2*NB ints
    const size_t smem_bytes = (size_t)capb * 8 + ((size_t)(capb + 3) / 4) * 4
                            + (size_t)2 * NB * 4;

    if (NB <= 128 && capb >= 128 && smem_bytes <= 64000 && ws_size >= need) {
        char* w = (char*)d_ws;
        int2*               sorted  = (int2*)w;               w += sorted_bytes;
        unsigned*           gcur    = (unsigned*)w;           w += gcur_bytes;
        unsigned long long* partXY  = (unsigned long long*)w; w += partXY_bytes;
        int*                partZ   = (int*)w;

        hipMemsetAsync(gcur, 0, (size_t)NB * 4, stream);
        hipMemsetAsync(energy, 0, sizeof(float), stream);
        p3_fused   <<<B1, T, smem_bytes, stream>>>(bv, dst, gcur, sorted, energy,
                                                   E, NB, GPB, cap);
        p4a_partial<<<NB << QS, T, 0, stream>>>(sorted, gcur, partXY, partZ, cap);
        p4b_merge  <<<(N + T - 1) / T, T, 0, stream>>>(partXY, partZ,
                                                       forces, analytic, N);
    } else {
        hipMemsetAsync(d_out, 0, (size_t)out_size * sizeof(float), stream);
        lj_fallback<<<(E + T - 1) / T, T, 0, stream>>>(bv, dst, energy, analytic, E);
        const int n3 = 3 * N;
        lj_scale<<<(n3 + T - 1) / T, T, 0, stream>>>(analytic, forces, n3);
    }
}